// Round 9
// baseline (255.079 us; speedup 1.0000x reference)
//
#include <hip/hip_runtime.h>
#include <hip/hip_bf16.h>

// GraphAttention2: N=6144, F=128, C=64, H=4. A ~1% sparse + self loops.
// R9: K1 fuses the A-scan (wave-per-row ballot -> CSR direct to global) with
// the projection GEMM as disjoint block ranges of one launch, overlapping the
// 24 us HBM A-stream with proj's VALU work. K2 is the barrier-free
// wave-per-row softmax+gather (R7 structure) reading the compact CSR.

#define N_NODES 6144
#define F_DIM   128
#define C_DIM   64
#define H_HEADS 4
#define HC      (H_HEADS * C_DIM)   // 256
#define MAXKW   128   // per-row cap; max degree ~96 (p=0.01), P(>=128)~1e-7

#define SCAN_BLOCKS (N_NODES / 4)            // 1536
#define PROJ_BLOCKS ((N_NODES / 64) * 8)     // 96 * 8 = 768

typedef unsigned short u16;
typedef float v4f __attribute__((ext_vector_type(4)));

// ---------------------------------------------------------------------------
// K1: blocks [0,1536): scan 4 rows (one per wave), ballot-compact neighbor
//     indices straight to nbr[i*MAXKW+..] (global; no LDS, no atomics).
//     blocks [1536,2304): per-head projections ->
//       featsB bf16 [N][H][C], feats2T fp32 [N][H][C], attsT/attnT [N][H].
// ---------------------------------------------------------------------------
__global__ __launch_bounds__(256) void scan_proj_kernel(
    const float* __restrict__ A, const float* __restrict__ X,
    const float* __restrict__ W1, const float* __restrict__ W2,
    const float* __restrict__ a_self, const float* __restrict__ a_neigh,
    u16* __restrict__ featsB, float* __restrict__ feats2T,
    float* __restrict__ attsT, float* __restrict__ attnT,
    int* __restrict__ nbr, int* __restrict__ nbr_cnt)
{
    const int bid = blockIdx.x;
    const int tid = threadIdx.x;

    __shared__ float  Xs[64][132];    // proj: [r][k], +4 pad (also ~67 KB total LDS)
    __shared__ float4 Ws4[128][17];   // proj: [k][c/4]

    if (bid < SCAN_BLOCKS) {
        // ---------------- scan: wave-per-row ----------------
        const int w    = tid >> 6;
        const int lane = tid & 63;
        const int i    = bid * 4 + w;

        const v4f* Arow = (const v4f*)(A + (size_t)i * N_NODES);
        const unsigned long long ltmask = (1ull << lane) - 1ull;
        int* nrow = nbr + (size_t)i * MAXKW;
        int base = 0;

        #pragma unroll
        for (int ch = 0; ch < 4; ++ch) {
            v4f v[6];
            #pragma unroll
            for (int g = 0; g < 6; ++g)
                v[g] = __builtin_nontemporal_load(Arow + lane + 64 * (ch * 6 + g));
            #pragma unroll
            for (int g = 0; g < 6; ++g) {
                const int col = 4 * (lane + 64 * (ch * 6 + g));
                #pragma unroll
                for (int m = 0; m < 4; ++m) {
                    const float x = (m == 0) ? v[g].x : (m == 1) ? v[g].y
                                  : (m == 2) ? v[g].z : v[g].w;
                    const bool p = (x > 0.5f);
                    const unsigned long long mask = __ballot(p);
                    if (p) {
                        const int pos = base + (int)__popcll(mask & ltmask);
                        if (pos < MAXKW) nrow[pos] = col + m;
                    }
                    base += (int)__popcll(mask);
                }
            }
        }
        if (lane == 0) nbr_cnt[i] = min(base, MAXKW);
        return;
    }

    // ---------------- proj: 64x64 tile, K=128 LDS-resident ----------------
    const int p     = bid - SCAN_BLOCKS;   // 0..767
    const int rt    = p % 96;
    const int z     = p / 96;              // 0..7
    const int h     = z >> 1;
    const int which = z & 1;

    const float* W = (which ? W2 : W1) + h * F_DIM * C_DIM;

    {
        const float4* Xg = (const float4*)(X + (size_t)rt * 64 * F_DIM);
        for (int u = tid; u < 64 * 32; u += 256) {
            const int r = u >> 5, q = u & 31;
            *(float4*)&Xs[r][4 * q] = Xg[u];
        }
        const float4* Wg = (const float4*)W;
        for (int u = tid; u < 128 * 16; u += 256) {
            Ws4[u >> 4][u & 15] = Wg[u];
        }
    }
    __syncthreads();

    const int tx = tid & 15;   // cols 4*tx..4*tx+3
    const int ty = tid >> 4;   // rows 4*ty..4*ty+3

    float acc[4][4] = {};
    for (int k = 0; k < 128; k += 4) {
        const float4 b0 = Ws4[k + 0][tx];
        const float4 b1 = Ws4[k + 1][tx];
        const float4 b2 = Ws4[k + 2][tx];
        const float4 b3 = Ws4[k + 3][tx];
        #pragma unroll
        for (int i = 0; i < 4; ++i) {
            const float4 x = *(const float4*)&Xs[4 * ty + i][k];
            acc[i][0] += x.x * b0.x + x.y * b1.x + x.z * b2.x + x.w * b3.x;
            acc[i][1] += x.x * b0.y + x.y * b1.y + x.z * b2.y + x.w * b3.y;
            acc[i][2] += x.x * b0.z + x.y * b1.z + x.z * b2.z + x.w * b3.z;
            acc[i][3] += x.x * b0.w + x.y * b1.w + x.z * b2.w + x.w * b3.w;
        }
    }

    __syncthreads();           // Xs free; reuse as C-tile scratch
    float* Ct = &Xs[0][0];     // viewed as [64][65]

    #pragma unroll
    for (int i = 0; i < 4; ++i) {
        const int r    = 4 * ty + i;
        const int node = rt * 64 + r;
        if (which == 0) {
            u16 p0 = __bfloat16_as_ushort(__float2bfloat16(acc[i][0]));
            u16 p1 = __bfloat16_as_ushort(__float2bfloat16(acc[i][1]));
            u16 p2 = __bfloat16_as_ushort(__float2bfloat16(acc[i][2]));
            u16 p3 = __bfloat16_as_ushort(__float2bfloat16(acc[i][3]));
            ushort4 pk; pk.x = p0; pk.y = p1; pk.z = p2; pk.w = p3;
            *(ushort4*)&featsB[(size_t)node * HC + h * C_DIM + 4 * tx] = pk;
            Ct[r * 65 + 4 * tx + 0] = acc[i][0];
            Ct[r * 65 + 4 * tx + 1] = acc[i][1];
            Ct[r * 65 + 4 * tx + 2] = acc[i][2];
            Ct[r * 65 + 4 * tx + 3] = acc[i][3];
        } else {
            *(float4*)&feats2T[(size_t)node * HC + h * C_DIM + 4 * tx] =
                make_float4(acc[i][0], acc[i][1], acc[i][2], acc[i][3]);
        }
    }

    if (which == 0) {
        __syncthreads();
        if (tid < 64) {
            const float* as_ = a_self  + h * C_DIM;
            const float* an_ = a_neigh + h * C_DIM;
            float s = 0.f, n = 0.f;
            #pragma unroll 8
            for (int c = 0; c < C_DIM; ++c) {
                const float v = Ct[tid * 65 + c];
                s += v * as_[c];
                n += v * an_[c];
            }
            const int node = rt * 64 + tid;
            attsT[node * H_HEADS + h] = s;
            attnT[node * H_HEADS + h] = n;
        }
    }
}

// ---------------------------------------------------------------------------
// K2: wave-per-row softmax + gather from CSR. Block = 4 waves = 4 rows,
// grid N/4 = 1536. NO __syncthreads -- waves fully independent.
// ---------------------------------------------------------------------------
__global__ __launch_bounds__(256) void gat_kernel(
    const int* __restrict__ nbr, const int* __restrict__ nbr_cnt,
    const u16* __restrict__ featsB, const float* __restrict__ feats2T,
    const float* __restrict__ attsT, const float* __restrict__ attnT,
    const float* __restrict__ bias,
    float* __restrict__ out)
{
    const int w    = threadIdx.x >> 6;   // wave id 0..3
    const int lane = threadIdx.x & 63;
    const int i    = blockIdx.x * 4 + w; // this wave's row

    __shared__ int    idxs[4][MAXKW];    // per-wave neighbor lists (2 KB)
    __shared__ float4 ewsT4[4][MAXKW];   // per-wave exp weights (8 KB)
    int*    idx_w = idxs[w];
    float4* ews_w = ewsT4[w];

    const int K = nbr_cnt[i];
    const int* nrow = nbr + (size_t)i * MAXKW;
    #pragma unroll
    for (int r = 0; r < 2; ++r) {
        const int k = lane + 64 * r;
        if (k < K) idx_w[k] = nrow[k];
    }

    // ---- exp(leaky(logit)); Z via butterfly. No max-pass (|logit| small).
    const float4 si4 = ((const float4*)attsT)[i];
    float zx = 0.f, zy = 0.f, zz = 0.f, zw = 0.f;
    #pragma unroll
    for (int r = 0; r < 2; ++r) {
        const int k = lane + 64 * r;
        if (k < K) {
            const float4 an = ((const float4*)attnT)[idx_w[k]];
            float l;
            float4 e4;
            l = si4.x + an.x; e4.x = __expf((l > 0.f) ? l : 0.2f * l);
            l = si4.y + an.y; e4.y = __expf((l > 0.f) ? l : 0.2f * l);
            l = si4.z + an.z; e4.z = __expf((l > 0.f) ? l : 0.2f * l);
            l = si4.w + an.w; e4.w = __expf((l > 0.f) ? l : 0.2f * l);
            ews_w[k] = e4;
            zx += e4.x; zy += e4.y; zz += e4.z; zw += e4.w;
        }
    }
    #pragma unroll
    for (int off = 32; off > 0; off >>= 1) {
        zx += __shfl_xor(zx, off);
        zy += __shfl_xor(zy, off);
        zz += __shfl_xor(zz, off);
        zw += __shfl_xor(zw, off);
    }
    const int hsel = lane >> 4;          // head owning channels 4*lane..4*lane+3
    const float zinv = 1.0f / ((hsel == 0) ? zx : (hsel == 1) ? zy
                             : (hsel == 2) ? zz : zw);

    // ---- gather: lane loads uint2 = 4 bf16 channels; one 512 B wave-load
    // covers the whole node (all heads). 8 loads in flight.
    const uint2* fb = (const uint2*)featsB;   // node j at fb[j*64 + lane]
    float a0 = 0.f, a1 = 0.f, a2 = 0.f, a3 = 0.f;

    #define UPFMA(q, wgt)                                                   \
        {                                                                   \
            a0 += (wgt) * __uint_as_float((q).x << 16);                     \
            a1 += (wgt) * __uint_as_float((q).x & 0xffff0000u);             \
            a2 += (wgt) * __uint_as_float((q).y << 16);                     \
            a3 += (wgt) * __uint_as_float((q).y & 0xffff0000u);             \
        }

    int k = 0;
    for (; k + 8 <= K; k += 8) {
        const int4 j0 = *(const int4*)&idx_w[k];      // LDS broadcast
        const int4 j1 = *(const int4*)&idx_w[k + 4];
        const float w0 = ((const float*)&ews_w[k + 0])[hsel];
        const float w1 = ((const float*)&ews_w[k + 1])[hsel];
        const float w2 = ((const float*)&ews_w[k + 2])[hsel];
        const float w3 = ((const float*)&ews_w[k + 3])[hsel];
        const float w4 = ((const float*)&ews_w[k + 4])[hsel];
        const float w5 = ((const float*)&ews_w[k + 5])[hsel];
        const float w6 = ((const float*)&ews_w[k + 6])[hsel];
        const float w7 = ((const float*)&ews_w[k + 7])[hsel];
        const uint2 q0 = fb[(size_t)j0.x * 64 + lane];
        const uint2 q1 = fb[(size_t)j0.y * 64 + lane];
        const uint2 q2 = fb[(size_t)j0.z * 64 + lane];
        const uint2 q3 = fb[(size_t)j0.w * 64 + lane];
        const uint2 q4 = fb[(size_t)j1.x * 64 + lane];
        const uint2 q5 = fb[(size_t)j1.y * 64 + lane];
        const uint2 q6 = fb[(size_t)j1.z * 64 + lane];
        const uint2 q7 = fb[(size_t)j1.w * 64 + lane];
        UPFMA(q0, w0) UPFMA(q1, w1) UPFMA(q2, w2) UPFMA(q3, w3)
        UPFMA(q4, w4) UPFMA(q5, w5) UPFMA(q6, w6) UPFMA(q7, w7)
    }
    for (; k < K; ++k) {
        const int   j  = idx_w[k];
        const float wg = ((const float*)&ews_w[k])[hsel];
        const uint2 q  = fb[(size_t)j * 64 + lane];
        UPFMA(q, wg)
    }
    #undef UPFMA

    // ---- epilogue: normalize, +feats2+bias, head-mean, relu.
    const float4 f2 = *(const float4*)&feats2T[(size_t)i * HC + 4 * lane];
    const float4 b4 = *(const float4*)&bias[4 * lane];
    float s0 = a0 * zinv + f2.x + b4.x;
    float s1 = a1 * zinv + f2.y + b4.y;
    float s2 = a2 * zinv + f2.z + b4.z;
    float s3 = a3 * zinv + f2.w + b4.w;
    s0 += __shfl_xor(s0, 16); s0 += __shfl_xor(s0, 32);
    s1 += __shfl_xor(s1, 16); s1 += __shfl_xor(s1, 32);
    s2 += __shfl_xor(s2, 16); s2 += __shfl_xor(s2, 32);
    s3 += __shfl_xor(s3, 16); s3 += __shfl_xor(s3, 32);
    if (lane < 16) {
        float4 o;
        o.x = fmaxf(0.25f * s0, 0.f);
        o.y = fmaxf(0.25f * s1, 0.f);
        o.z = fmaxf(0.25f * s2, 0.f);
        o.w = fmaxf(0.25f * s3, 0.f);
        *(float4*)&out[(size_t)i * C_DIM + 4 * lane] = o;
    }
}

extern "C" void kernel_launch(void* const* d_in, const int* in_sizes, int n_in,
                              void* d_out, int out_size, void* d_ws, size_t ws_size,
                              hipStream_t stream) {
    const float* X       = (const float*)d_in[0];
    const float* A       = (const float*)d_in[1];
    const float* W1      = (const float*)d_in[2];
    const float* W2      = (const float*)d_in[3];
    const float* a_self  = (const float*)d_in[4];
    const float* a_neigh = (const float*)d_in[5];
    const float* bias    = (const float*)d_in[6];
    float* out = (float*)d_out;

    // Workspace: feats2T fp32 | attsT | attnT | featsB bf16 | nbr | cnt (~13 MB)
    float* ws      = (float*)d_ws;
    float* feats2T = ws;                                    // N*HC fp32
    float* attsT   = feats2T + (size_t)N_NODES * HC;        // N*H
    float* attnT   = attsT   + (size_t)N_NODES * H_HEADS;
    u16*   featsB  = (u16*)(attnT + (size_t)N_NODES * H_HEADS);   // N*HC bf16
    int*   nbr     = (int*)(featsB + (size_t)N_NODES * HC);       // N*MAXKW
    int*   nbr_cnt = nbr + (size_t)N_NODES * MAXKW;               // N

    scan_proj_kernel<<<SCAN_BLOCKS + PROJ_BLOCKS, 256, 0, stream>>>(
        A, X, W1, W2, a_self, a_neigh,
        featsB, feats2T, attsT, attnT, nbr, nbr_cnt);

    gat_kernel<<<N_NODES / 4, 256, 0, stream>>>(
        nbr, nbr_cnt, featsB, feats2T, attsT, attnT, bias, out);
}

// Round 10
// 246.941 us; speedup vs baseline: 1.0330x; 1.0330x over previous
//
#include <hip/hip_runtime.h>
#include <hip/hip_bf16.h>

// GraphAttention2: N=6144, F=128, C=64, H=4. A ~1% sparse + self loops.
// R10: R7's wave-per-row ballot scan (full compaction first, no FIFO
// interleave) + R8's fused gather (exp folded into gather loop, wave-uniform
// attnT loads = 1 line/neighbor, deferred per-lane normalization). Deletes
// R7's phase B (64-way uncoalesced attnT pass, ews LDS, Z butterflies).

#define N_NODES 6144
#define F_DIM   128
#define C_DIM   64
#define H_HEADS 4
#define HC      (H_HEADS * C_DIM)   // 256
#define MAXKW   128   // per-row cap; max degree ~96 (p=0.01), P(>=128)~1e-7

typedef unsigned short u16;
typedef float v4f __attribute__((ext_vector_type(4)));

// ---------------------------------------------------------------------------
// Kernel 1: per-head projections (R7 verbatim).
//   featsB  : bf16 [N][H][C]  (512 B per node)  -- gather operand
//   feats2T : fp32 [N][H][C]                    -- read-once residual
//   attsT/attnT : fp32 [N][H] (16 B per node)
// ---------------------------------------------------------------------------
__global__ __launch_bounds__(256) void proj_kernel(
    const float* __restrict__ X,
    const float* __restrict__ W1, const float* __restrict__ W2,
    const float* __restrict__ a_self, const float* __restrict__ a_neigh,
    u16* __restrict__ featsB, float* __restrict__ feats2T,
    float* __restrict__ attsT, float* __restrict__ attnT)
{
    const int rt    = blockIdx.x;
    const int z     = blockIdx.y;
    const int h     = z >> 1;
    const int which = z & 1;

    const float* W = (which ? W2 : W1) + h * F_DIM * C_DIM;

    __shared__ float  Xs[64][132];    // [r][k], +4 pad
    __shared__ float4 Ws4[128][17];   // [k][c/4], +1 float4 pad

    const int tid = threadIdx.x;

    {
        const float4* Xg = (const float4*)(X + (size_t)rt * 64 * F_DIM);
        for (int u = tid; u < 64 * 32; u += 256) {
            const int r = u >> 5, q = u & 31;
            *(float4*)&Xs[r][4 * q] = Xg[u];
        }
        const float4* Wg = (const float4*)W;
        for (int u = tid; u < 128 * 16; u += 256) {
            Ws4[u >> 4][u & 15] = Wg[u];
        }
    }
    __syncthreads();

    const int tx = tid & 15;   // cols 4*tx..4*tx+3
    const int ty = tid >> 4;   // rows 4*ty..4*ty+3

    float acc[4][4] = {};
    for (int k = 0; k < 128; k += 4) {
        const float4 b0 = Ws4[k + 0][tx];
        const float4 b1 = Ws4[k + 1][tx];
        const float4 b2 = Ws4[k + 2][tx];
        const float4 b3 = Ws4[k + 3][tx];
        #pragma unroll
        for (int i = 0; i < 4; ++i) {
            const float4 x = *(const float4*)&Xs[4 * ty + i][k];
            acc[i][0] += x.x * b0.x + x.y * b1.x + x.z * b2.x + x.w * b3.x;
            acc[i][1] += x.x * b0.y + x.y * b1.y + x.z * b2.y + x.w * b3.y;
            acc[i][2] += x.x * b0.z + x.y * b1.z + x.z * b2.z + x.w * b3.z;
            acc[i][3] += x.x * b0.w + x.y * b1.w + x.z * b2.w + x.w * b3.w;
        }
    }

    __syncthreads();           // Xs free; reuse as C-tile scratch
    float* Ct = &Xs[0][0];     // viewed as [64][65]

    #pragma unroll
    for (int i = 0; i < 4; ++i) {
        const int r    = 4 * ty + i;
        const int node = rt * 64 + r;
        if (which == 0) {
            u16 p0 = __bfloat16_as_ushort(__float2bfloat16(acc[i][0]));
            u16 p1 = __bfloat16_as_ushort(__float2bfloat16(acc[i][1]));
            u16 p2 = __bfloat16_as_ushort(__float2bfloat16(acc[i][2]));
            u16 p3 = __bfloat16_as_ushort(__float2bfloat16(acc[i][3]));
            ushort4 pk; pk.x = p0; pk.y = p1; pk.z = p2; pk.w = p3;
            *(ushort4*)&featsB[(size_t)node * HC + h * C_DIM + 4 * tx] = pk;
            Ct[r * 65 + 4 * tx + 0] = acc[i][0];
            Ct[r * 65 + 4 * tx + 1] = acc[i][1];
            Ct[r * 65 + 4 * tx + 2] = acc[i][2];
            Ct[r * 65 + 4 * tx + 3] = acc[i][3];
        } else {
            *(float4*)&feats2T[(size_t)node * HC + h * C_DIM + 4 * tx] =
                make_float4(acc[i][0], acc[i][1], acc[i][2], acc[i][3]);
        }
    }

    if (which == 0) {
        __syncthreads();
        if (tid < 64) {
            const float* as_ = a_self  + h * C_DIM;
            const float* an_ = a_neigh + h * C_DIM;
            float s = 0.f, n = 0.f;
            #pragma unroll 8
            for (int c = 0; c < C_DIM; ++c) {
                const float v = Ct[tid * 65 + c];
                s += v * as_[c];
                n += v * an_[c];
            }
            const int node = rt * 64 + tid;
            attsT[node * H_HEADS + h] = s;
            attnT[node * H_HEADS + h] = n;
        }
    }
}

// ---------------------------------------------------------------------------
// Kernel 2: wave-per-row. Block = 4 waves = 4 rows, grid N/4 = 1536.
// No __syncthreads. Scan compacts the full row FIRST (R7); then one fused
// gather loop: attn scalar (wave-uniform j, 1 line) + feats uint2 per batch,
// exp in-loop, deferred normalization (z per lane, no reduction).
// ---------------------------------------------------------------------------
__global__ __launch_bounds__(256) void agg_kernel(
    const float* __restrict__ A,
    const u16* __restrict__ featsB, const float* __restrict__ feats2T,
    const float* __restrict__ attsT, const float* __restrict__ attnT,
    const float* __restrict__ bias,
    float* __restrict__ out)
{
    const int w    = threadIdx.x >> 6;   // wave id 0..3
    const int lane = threadIdx.x & 63;
    const int i    = blockIdx.x * 4 + w; // this wave's row

    __shared__ int idxs[4][MAXKW];       // per-wave neighbor lists (2 KB)
    int* idx_w = idxs[w];

    // ---- Phase A: scan row i, ballot compaction (R7 verbatim).
    const v4f* Arow = (const v4f*)(A + (size_t)i * N_NODES);
    const unsigned long long ltmask = (1ull << lane) - 1ull;
    int base = 0;
    #pragma unroll
    for (int ch = 0; ch < 4; ++ch) {     // 4 chunks x 6 groups x 64 lanes x float4
        v4f v[6];
        #pragma unroll
        for (int g = 0; g < 6; ++g)
            v[g] = __builtin_nontemporal_load(Arow + lane + 64 * (ch * 6 + g));
        #pragma unroll
        for (int g = 0; g < 6; ++g) {
            const int col = 4 * (lane + 64 * (ch * 6 + g));
            #pragma unroll
            for (int m = 0; m < 4; ++m) {
                const float x = (m == 0) ? v[g].x : (m == 1) ? v[g].y
                              : (m == 2) ? v[g].z : v[g].w;
                const bool p = (x > 0.5f);
                const unsigned long long mask = __ballot(p);
                if (p) {
                    const int pos = base + (int)__popcll(mask & ltmask);
                    if (pos < MAXKW) idx_w[pos] = col + m;
                }
                base += (int)__popcll(mask);
            }
        }
    }
    const int K = min(base, MAXKW);

    // ---- Phase C: fused exp + gather, deferred normalization.
    const int    hsel = lane >> 4;                   // head for channels 4l..4l+3
    const float  si   = attsT[4 * i + hsel];         // self logit (this head)
    const float* anp  = attnT + hsel;                // attnT[4*j + hsel]; all 64
                                                     // lanes of a wave hit the
                                                     // SAME 16B line per j
    const uint2* fb   = (const uint2*)featsB;        // node j at fb[j*64+lane]

    float a0 = 0.f, a1 = 0.f, a2 = 0.f, a3 = 0.f;   // channel accumulators
    float z  = 0.f;                                  // sum of e (per lane)

    #define UPFMA(q, e)                                                     \
        {                                                                   \
            a0 += (e) * __uint_as_float((q).x << 16);                       \
            a1 += (e) * __uint_as_float((q).x & 0xffff0000u);               \
            a2 += (e) * __uint_as_float((q).y << 16);                       \
            a3 += (e) * __uint_as_float((q).y & 0xffff0000u);               \
        }
    #define EXPW(an, e)                                                     \
        float e;                                                            \
        {                                                                   \
            float l = si + (an);                                            \
            l = (l > 0.f) ? l : 0.2f * l;                                   \
            e = __expf(l);                                                  \
        }

    int k = 0;
    for (; k + 8 <= K; k += 8) {
        const int4 j0 = *(const int4*)&idx_w[k];      // LDS b128 x2
        const int4 j1 = *(const int4*)&idx_w[k + 4];
        // 8 attn scalars (1 line each) + 8 feats uint2, all independent.
        const float an0 = anp[4 * (size_t)j0.x];
        const float an1 = anp[4 * (size_t)j0.y];
        const float an2 = anp[4 * (size_t)j0.z];
        const float an3 = anp[4 * (size_t)j0.w];
        const float an4 = anp[4 * (size_t)j1.x];
        const float an5 = anp[4 * (size_t)j1.y];
        const float an6 = anp[4 * (size_t)j1.z];
        const float an7 = anp[4 * (size_t)j1.w];
        const uint2 q0 = fb[(size_t)j0.x * 64 + lane];
        const uint2 q1 = fb[(size_t)j0.y * 64 + lane];
        const uint2 q2 = fb[(size_t)j0.z * 64 + lane];
        const uint2 q3 = fb[(size_t)j0.w * 64 + lane];
        const uint2 q4 = fb[(size_t)j1.x * 64 + lane];
        const uint2 q5 = fb[(size_t)j1.y * 64 + lane];
        const uint2 q6 = fb[(size_t)j1.z * 64 + lane];
        const uint2 q7 = fb[(size_t)j1.w * 64 + lane];
        EXPW(an0, e0) EXPW(an1, e1) EXPW(an2, e2) EXPW(an3, e3)
        EXPW(an4, e4) EXPW(an5, e5) EXPW(an6, e6) EXPW(an7, e7)
        z += (e0 + e1 + e2 + e3) + (e4 + e5 + e6 + e7);
        UPFMA(q0, e0) UPFMA(q1, e1) UPFMA(q2, e2) UPFMA(q3, e3)
        UPFMA(q4, e4) UPFMA(q5, e5) UPFMA(q6, e6) UPFMA(q7, e7)
    }
    for (; k < K; ++k) {
        const int   j  = idx_w[k];
        const float an = anp[4 * (size_t)j];
        const uint2 q  = fb[(size_t)j * 64 + lane];
        EXPW(an, e)
        z += e;
        UPFMA(q, e)
    }
    #undef UPFMA
    #undef EXPW

    // ---- Epilogue: normalize, +feats2+bias, head-mean, relu.
    const float zinv = 1.0f / z;
    const float4 f2 = *(const float4*)&feats2T[(size_t)i * HC + 4 * lane];
    const float4 b4 = *(const float4*)&bias[4 * lane];
    float s0 = a0 * zinv + f2.x + b4.x;
    float s1 = a1 * zinv + f2.y + b4.y;
    float s2 = a2 * zinv + f2.z + b4.z;
    float s3 = a3 * zinv + f2.w + b4.w;
    s0 += __shfl_xor(s0, 16); s0 += __shfl_xor(s0, 32);
    s1 += __shfl_xor(s1, 16); s1 += __shfl_xor(s1, 32);
    s2 += __shfl_xor(s2, 16); s2 += __shfl_xor(s2, 32);
    s3 += __shfl_xor(s3, 16); s3 += __shfl_xor(s3, 32);
    if (lane < 16) {
        float4 o;
        o.x = fmaxf(0.25f * s0, 0.f);
        o.y = fmaxf(0.25f * s1, 0.f);
        o.z = fmaxf(0.25f * s2, 0.f);
        o.w = fmaxf(0.25f * s3, 0.f);
        *(float4*)&out[(size_t)i * C_DIM + 4 * lane] = o;
    }
}

extern "C" void kernel_launch(void* const* d_in, const int* in_sizes, int n_in,
                              void* d_out, int out_size, void* d_ws, size_t ws_size,
                              hipStream_t stream) {
    const float* X       = (const float*)d_in[0];
    const float* A       = (const float*)d_in[1];
    const float* W1      = (const float*)d_in[2];
    const float* W2      = (const float*)d_in[3];
    const float* a_self  = (const float*)d_in[4];
    const float* a_neigh = (const float*)d_in[5];
    const float* bias    = (const float*)d_in[6];
    float* out = (float*)d_out;

    // Workspace: feats2T fp32 | attsT | attnT | featsB bf16 (~9.6 MB total)
    float* ws      = (float*)d_ws;
    float* feats2T = ws;                                    // N*HC fp32
    float* attsT   = feats2T + (size_t)N_NODES * HC;        // N*H
    float* attnT   = attsT   + (size_t)N_NODES * H_HEADS;
    u16*   featsB  = (u16*)(attnT + (size_t)N_NODES * H_HEADS);  // N*HC bf16

    dim3 grid1(N_NODES / 64, H_HEADS * 2);
    proj_kernel<<<grid1, 256, 0, stream>>>(X, W1, W2, a_self, a_neigh,
                                           featsB, feats2T, attsT, attnT);

    agg_kernel<<<N_NODES / 4, 256, 0, stream>>>(A, featsB, feats2T, attsT, attnT, bias, out);
}